// Round 11
// baseline (160.326 us; speedup 1.0000x reference)
//
#include <hip/hip_runtime.h>
#include <math.h>

#define NTOK   8192
#define HID    2048
#define NEXP   64
#define TOPK   8
#define NFLAT  (NTOK * TOPK)      // 65536
#define NB     1024               // route blocks (8 tokens each)
#define TPB    8                  // tokens per route block
#define CGRID  1024               // k_copy persistent blocks (8 tokens each)
#define CITER  (NTOK / CGRID)     // 8
#define OUT_GS_OFF  ((size_t)NFLAT * HID)        // 134217728
#define OUT_LB_OFF  (OUT_GS_OFF + NEXP)          // 134217792

typedef float f32x4 __attribute__((ext_vector_type(4)));

// ---------------------------------------------------------------------------
// K1: per-token softmax + top-8 + per-block expert bitmasks (stable rank) +
// prob partials. 1024 blocks x 256 threads (4 waves), 8 tokens/block ->
// 2 tokens per wave (chain halved vs R10) and 4 blocks/CU.
// lane == expert id. Entry metadata packed as e | (rank<<8).
// ---------------------------------------------------------------------------
__global__ __launch_bounds__(256) void k_route(const float* __restrict__ logits,
                                               int*   __restrict__ e_rank,   // [NFLAT]
                                               float* __restrict__ flat_w,   // [NFLAT]
                                               int*   __restrict__ counts,   // [NEXP][NB]
                                               float* __restrict__ probpart) // [NEXP][NB]
{
    __shared__ float sm[4][64];
    __shared__ unsigned mask[64];     // bit ti set if block-token ti chose expert
    const int tid  = threadIdx.x;
    const int lane = tid & 63;
    const int wave = tid >> 6;
    if (tid < 64) mask[tid] = 0u;
    float acc = 0.f;
    __syncthreads();

    int   sel_i[2];
    float sel_v[2];
    float sum8s[2];

    #pragma unroll
    for (int it = 0; it < 2; ++it) {
        const int ti    = it * 4 + wave;            // token index within block
        const int token = blockIdx.x * TPB + ti;
        const float lg = logits[(size_t)token * NEXP + lane];
        // softmax across the 64-lane wave
        float m = lg;
        #pragma unroll
        for (int off = 32; off; off >>= 1) m = fmaxf(m, __shfl_xor(m, off));
        const float ex = expf(lg - m);
        float s = ex;
        #pragma unroll
        for (int off = 32; off; off >>= 1) s += __shfl_xor(s, off);
        const float p = ex / s;
        acc += p;

        // top-8: iterative max with lower-index tie-break (lax.top_k semantics)
        float v = p;
        float mysel_v = 0.f; int mysel_i = 0; float sum8 = 0.f;
        #pragma unroll
        for (int k = 0; k < TOPK; ++k) {
            float mv = v; int mi = lane;
            #pragma unroll
            for (int off = 32; off; off >>= 1) {
                const float ov = __shfl_xor(mv, off);
                const int   oi = __shfl_xor(mi, off);
                if (ov > mv || (ov == mv && oi < mi)) { mv = ov; mi = oi; }
            }
            if (lane == k)  { mysel_v = mv; mysel_i = mi; }
            if (lane == mi) v = -1.f;   // probs > 0, so -1 acts as -inf
            sum8 += mv;
        }
        sel_i[it] = mysel_i; sel_v[it] = mysel_v; sum8s[it] = sum8;
        if (lane < TOPK) atomicOr(&mask[mysel_i], 1u << ti);
    }

    sm[wave][lane] = acc;
    __syncthreads();

    if (tid < 64) {
        counts  [(size_t)tid * NB + blockIdx.x] = (int)__popc(mask[tid]);
        probpart[(size_t)tid * NB + blockIdx.x] =
            sm[0][tid] + sm[1][tid] + sm[2][tid] + sm[3][tid];
    }

    // stable intra-block rank: # earlier block-tokens that chose the same expert
    #pragma unroll
    for (int it = 0; it < 2; ++it) {
        const int ti    = it * 4 + wave;
        const int token = blockIdx.x * TPB + ti;
        if (lane < TOPK) {
            const int e    = sel_i[it];
            const int rank = (int)__popc(mask[e] & ((1u << ti) - 1u));
            e_rank[(size_t)token * TOPK + lane] = e | (rank << 8);
            flat_w[(size_t)token * TOPK + lane] = sel_v[it] / sum8s[it];
        }
    }
}

// ---------------------------------------------------------------------------
// K2: single block, 256 threads. Two-level scan over [NEXP][NB=1024]
// histograms; thread t -> expert e=t/4, quarter q=t%4 (256 blocks each).
// group_sizes + lb_loss out. [separate dispatch = free coherence, R7 lesson]
// ---------------------------------------------------------------------------
__global__ __launch_bounds__(256) void k_scan(const int*   __restrict__ counts,   // [NEXP][NB]
                                              const float* __restrict__ probpart, // [NEXP][NB]
                                              int*   __restrict__ blockoff,       // [NEXP][NB]
                                              float* __restrict__ out_gs,
                                              float* __restrict__ out_lb) {
    __shared__ int   part_c[64][4];
    __shared__ float part_p[64][4];
    __shared__ int   qoff[64][4];
    __shared__ int   totals[64];
    __shared__ float psums[64];
    __shared__ int   basesm[64];
    const int t = threadIdx.x;
    const int e = t >> 2;
    const int q = t & 3;

    int tot = 0; float ps = 0.f;
    const size_t base = (size_t)e * NB + q * (NB / 4);
    for (int b = 0; b < NB / 4; b += 4) {
        const int4   c  = *(const int4*)  &counts  [base + b];
        const float4 pp = *(const float4*)&probpart[base + b];
        tot += c.x + c.y + c.z + c.w;
        ps  += pp.x + pp.y + pp.z + pp.w;
    }
    part_c[e][q] = tot; part_p[e][q] = ps;
    __syncthreads();

    if (t < 64) {
        const int c0 = part_c[t][0], c1 = part_c[t][1],
                  c2 = part_c[t][2], c3 = part_c[t][3];
        qoff[t][0] = 0;
        qoff[t][1] = c0;
        qoff[t][2] = c0 + c1;
        qoff[t][3] = c0 + c1 + c2;
        totals[t]  = c0 + c1 + c2 + c3;
        psums[t]   = part_p[t][0] + part_p[t][1] + part_p[t][2] + part_p[t][3];
    }
    __syncthreads();

    if (t == 0) {
        int bacc = 0; float lb = 0.f;
        for (int i = 0; i < 64; ++i) {
            basesm[i] = bacc;
            bacc += totals[i];
            lb += ((float)totals[i] * (1.f / 8192.f)) * (psums[i] * (1.f / 8192.f));
        }
        *out_lb = 0.01f * lb;
    }
    __syncthreads();

    if (t < 64) out_gs[t] = (float)totals[t];

    int run = basesm[e] + qoff[e][q];
    for (int b = 0; b < NB / 4; b += 4) {
        const int4 c = *(const int4*)&counts[base + b];
        int4 o;
        o.x = run;
        o.y = o.x + c.x;
        o.z = o.y + c.y;
        o.w = o.z + c.z;
        run = o.w + c.w;
        *(int4*)&blockoff[base + b] = o;
    }
}

// ---------------------------------------------------------------------------
// K3: persistent scatter copy, 1024 blocks x 8 tokens, double-buffered
// pipeline with nt stores (champion structure). New: per-token destinations
// sorted ascending (rank-by-comparison) so each wave's 8 store bursts walk
// monotonically increasing addresses -> better DRAM page locality.
// ---------------------------------------------------------------------------
__global__ __launch_bounds__(256) void k_copy(const float* __restrict__ x,
                                              const int*   __restrict__ e_rank,
                                              const float* __restrict__ flat_w,
                                              const int*   __restrict__ blockoff,
                                              float*       __restrict__ out) {
    __shared__ int   s_raw[2][8];
    __shared__ float s_wraw[2][8];
    __shared__ int   s_pos[2][8];
    __shared__ float s_w[2][8];
    const int t = threadIdx.x;

    int tok = blockIdx.x;
    if (t < TOPK) {
        const int er = e_rank[(size_t)tok * TOPK + t];
        s_raw[0][t]  = blockoff[(size_t)(er & 0xff) * NB + (tok >> 3)] + (er >> 8);
        s_wraw[0][t] = flat_w[(size_t)tok * TOPK + t];
    }
    const f32x4* __restrict__ src0 = (const f32x4*)(x + (size_t)tok * HID);
    f32x4 a = src0[t];
    f32x4 b = src0[t + 256];
    __syncthreads();
    if (t < TOPK) {
        // sort (pos,w) pairs ascending by pos: rank = # entries smaller
        // (positions are distinct rows -> ranks are a permutation of 0..7)
        const int myp = s_raw[0][t];
        int r = 0;
        #pragma unroll
        for (int j = 0; j < TOPK; ++j) r += (s_raw[0][j] < myp);
        s_pos[0][r] = myp;
        s_w[0][r]   = s_wraw[0][t];
    }
    __syncthreads();

    #pragma unroll
    for (int it = 0; it < CITER; ++it) {
        const int cur = it & 1;
        const int nxt = cur ^ 1;
        const int ntok = tok + CGRID;
        f32x4 a1 = a, b1 = b;
        if (it < CITER - 1) {
            if (t < TOPK) {
                const int er = e_rank[(size_t)ntok * TOPK + t];
                s_raw[nxt][t]  = blockoff[(size_t)(er & 0xff) * NB + (ntok >> 3)] + (er >> 8);
                s_wraw[nxt][t] = flat_w[(size_t)ntok * TOPK + t];
            }
            const f32x4* __restrict__ src1 = (const f32x4*)(x + (size_t)ntok * HID);
            a1 = src1[t];
            b1 = src1[t + 256];
        }
        #pragma unroll
        for (int k = 0; k < TOPK; ++k) {
            const float w = s_w[cur][k];
            f32x4* dst = (f32x4*)(out + (size_t)s_pos[cur][k] * HID);
            __builtin_nontemporal_store(a * w, dst + t);
            __builtin_nontemporal_store(b * w, dst + t + 256);
        }
        __syncthreads();   // next-iter raw meta visible; cur buffers reusable
        if (it < CITER - 1 && t < TOPK) {
            const int myp = s_raw[nxt][t];
            int r = 0;
            #pragma unroll
            for (int j = 0; j < TOPK; ++j) r += (s_raw[nxt][j] < myp);
            s_pos[nxt][r] = myp;
            s_w[nxt][r]   = s_wraw[nxt][t];
        }
        __syncthreads();   // sorted buffers ready for next iter
        a = a1; b = b1; tok = ntok;
    }
}

extern "C" void kernel_launch(void* const* d_in, const int* in_sizes, int n_in,
                              void* d_out, int out_size, void* d_ws, size_t ws_size,
                              hipStream_t stream) {
    const float* x      = (const float*)d_in[0];   // inputs_flat [8192,2048]
    const float* logits = (const float*)d_in[1];   // router_logits [8192,64]
    float* out = (float*)d_out;

    char* ws = (char*)d_ws;
    int*   e_rank   = (int*)  (ws + 0);            // 65536*4 = 262144
    float* flat_w   = (float*)(ws + 262144);       // 262144
    int*   counts   = (int*)  (ws + 524288);       // 64*1024*4 = 262144
    int*   blockoff = (int*)  (ws + 786432);       // 262144
    float* probpart = (float*)(ws + 1048576);      // 262144

    k_route<<<NB, 256, 0, stream>>>(logits, e_rank, flat_w, counts, probpart);
    k_scan <<<1, 256, 0, stream>>>(counts, probpart, blockoff,
                                   out + OUT_GS_OFF, out + OUT_LB_OFF);
    k_copy <<<CGRID, 256, 0, stream>>>(x, e_rank, flat_w, blockoff, out);
}

// Round 12
// 152.271 us; speedup vs baseline: 1.0529x; 1.0529x over previous
//
#include <hip/hip_runtime.h>
#include <math.h>

#define NTOK   8192
#define HID    2048
#define NEXP   64
#define TOPK   8
#define NFLAT  (NTOK * TOPK)      // 65536
#define NB     512                // route blocks (16 tokens each)
#define TPB    16                 // tokens per route block
#define CGRID  1024               // k_copy persistent blocks (8 tokens each)
#define CITER  (NTOK / CGRID)     // 8
#define OUT_GS_OFF  ((size_t)NFLAT * HID)        // 134217728
#define OUT_LB_OFF  (OUT_GS_OFF + NEXP)          // 134217792

typedef float f32x4 __attribute__((ext_vector_type(4)));

// ---------------------------------------------------------------------------
// K1: per-token softmax + top-8 + per-block expert bitmasks (stable rank) +
// prob partials. 512 blocks x 256 threads (4 waves), 16 tokens/block ->
// 4 tokens per wave, 2 blocks/CU. [R10-proven champion]
// lane == expert id. Entry metadata packed as e | (rank<<8).
// ---------------------------------------------------------------------------
__global__ __launch_bounds__(256) void k_route(const float* __restrict__ logits,
                                               int*   __restrict__ e_rank,   // [NFLAT]
                                               float* __restrict__ flat_w,   // [NFLAT]
                                               int*   __restrict__ counts,   // [NEXP][NB]
                                               float* __restrict__ probpart) // [NEXP][NB]
{
    __shared__ float sm[4][64];
    __shared__ unsigned mask[64];     // bit ti set if block-token ti chose expert
    const int tid  = threadIdx.x;
    const int lane = tid & 63;
    const int wave = tid >> 6;
    if (tid < 64) mask[tid] = 0u;
    float acc = 0.f;
    __syncthreads();

    int   sel_i[4];
    float sel_v[4];
    float sum8s[4];

    #pragma unroll
    for (int it = 0; it < 4; ++it) {
        const int ti    = it * 4 + wave;            // token index within block
        const int token = blockIdx.x * TPB + ti;
        const float lg = logits[(size_t)token * NEXP + lane];
        // softmax across the 64-lane wave
        float m = lg;
        #pragma unroll
        for (int off = 32; off; off >>= 1) m = fmaxf(m, __shfl_xor(m, off));
        const float ex = expf(lg - m);
        float s = ex;
        #pragma unroll
        for (int off = 32; off; off >>= 1) s += __shfl_xor(s, off);
        const float p = ex / s;
        acc += p;

        // top-8: iterative max with lower-index tie-break (lax.top_k semantics)
        float v = p;
        float mysel_v = 0.f; int mysel_i = 0; float sum8 = 0.f;
        #pragma unroll
        for (int k = 0; k < TOPK; ++k) {
            float mv = v; int mi = lane;
            #pragma unroll
            for (int off = 32; off; off >>= 1) {
                const float ov = __shfl_xor(mv, off);
                const int   oi = __shfl_xor(mi, off);
                if (ov > mv || (ov == mv && oi < mi)) { mv = ov; mi = oi; }
            }
            if (lane == k)  { mysel_v = mv; mysel_i = mi; }
            if (lane == mi) v = -1.f;   // probs > 0, so -1 acts as -inf
            sum8 += mv;
        }
        sel_i[it] = mysel_i; sel_v[it] = mysel_v; sum8s[it] = sum8;
        if (lane < TOPK) atomicOr(&mask[mysel_i], 1u << ti);
    }

    sm[wave][lane] = acc;
    __syncthreads();

    if (tid < 64) {
        counts  [(size_t)tid * NB + blockIdx.x] = (int)__popc(mask[tid]);
        probpart[(size_t)tid * NB + blockIdx.x] =
            sm[0][tid] + sm[1][tid] + sm[2][tid] + sm[3][tid];
    }

    // stable intra-block rank: # earlier block-tokens that chose the same expert
    #pragma unroll
    for (int it = 0; it < 4; ++it) {
        const int ti    = it * 4 + wave;
        const int token = blockIdx.x * TPB + ti;
        if (lane < TOPK) {
            const int e    = sel_i[it];
            const int rank = (int)__popc(mask[e] & ((1u << ti) - 1u));
            e_rank[(size_t)token * TOPK + lane] = e | (rank << 8);
            flat_w[(size_t)token * TOPK + lane] = sel_v[it] / sum8s[it];
        }
    }
}

// ---------------------------------------------------------------------------
// K2: single block, 256 threads. Two-level scan over [NEXP][NB=512]
// histograms; thread t -> expert e=t/4, quarter q=t%4 (128 blocks each).
// group_sizes + lb_loss out. [separate dispatch = free coherence, R7 lesson]
// ---------------------------------------------------------------------------
__global__ __launch_bounds__(256) void k_scan(const int*   __restrict__ counts,   // [NEXP][NB]
                                              const float* __restrict__ probpart, // [NEXP][NB]
                                              int*   __restrict__ blockoff,       // [NEXP][NB]
                                              float* __restrict__ out_gs,
                                              float* __restrict__ out_lb) {
    __shared__ int   part_c[64][4];
    __shared__ float part_p[64][4];
    __shared__ int   qoff[64][4];
    __shared__ int   totals[64];
    __shared__ float psums[64];
    __shared__ int   basesm[64];
    const int t = threadIdx.x;
    const int e = t >> 2;
    const int q = t & 3;

    int tot = 0; float ps = 0.f;
    const size_t base = (size_t)e * NB + q * (NB / 4);
    for (int b = 0; b < NB / 4; b += 4) {
        const int4   c  = *(const int4*)  &counts  [base + b];
        const float4 pp = *(const float4*)&probpart[base + b];
        tot += c.x + c.y + c.z + c.w;
        ps  += pp.x + pp.y + pp.z + pp.w;
    }
    part_c[e][q] = tot; part_p[e][q] = ps;
    __syncthreads();

    if (t < 64) {
        const int c0 = part_c[t][0], c1 = part_c[t][1],
                  c2 = part_c[t][2], c3 = part_c[t][3];
        qoff[t][0] = 0;
        qoff[t][1] = c0;
        qoff[t][2] = c0 + c1;
        qoff[t][3] = c0 + c1 + c2;
        totals[t]  = c0 + c1 + c2 + c3;
        psums[t]   = part_p[t][0] + part_p[t][1] + part_p[t][2] + part_p[t][3];
    }
    __syncthreads();

    if (t == 0) {
        int bacc = 0; float lb = 0.f;
        for (int i = 0; i < 64; ++i) {
            basesm[i] = bacc;
            bacc += totals[i];
            lb += ((float)totals[i] * (1.f / 8192.f)) * (psums[i] * (1.f / 8192.f));
        }
        *out_lb = 0.01f * lb;
    }
    __syncthreads();

    if (t < 64) out_gs[t] = (float)totals[t];

    int run = basesm[e] + qoff[e][q];
    for (int b = 0; b < NB / 4; b += 4) {
        const int4 c = *(const int4*)&counts[base + b];
        int4 o;
        o.x = run;
        o.y = o.x + c.x;
        o.z = o.y + c.y;
        o.w = o.z + c.z;
        run = o.w + c.w;
        *(int4*)&blockoff[base + b] = o;
    }
}

// ---------------------------------------------------------------------------
// K3: persistent scatter copy, 1024 blocks x 8 tokens, double-buffered
// pipeline with nt stores — the R8/R9/R10-proven champion (one barrier per
// iteration, no dest-sort: R11 proved added sync in the steady loop is loss).
// ---------------------------------------------------------------------------
__global__ __launch_bounds__(256) void k_copy(const float* __restrict__ x,
                                              const int*   __restrict__ e_rank,
                                              const float* __restrict__ flat_w,
                                              const int*   __restrict__ blockoff,
                                              float*       __restrict__ out) {
    __shared__ int   s_pos[2][8];
    __shared__ float s_w[2][8];
    const int t = threadIdx.x;

    int tok = blockIdx.x;
    if (t < TOPK) {
        const int er = e_rank[(size_t)tok * TOPK + t];
        s_pos[0][t] = blockoff[(size_t)(er & 0xff) * NB + (tok >> 4)] + (er >> 8);
        s_w[0][t]   = flat_w[(size_t)tok * TOPK + t];
    }
    const f32x4* __restrict__ src0 = (const f32x4*)(x + (size_t)tok * HID);
    f32x4 a = src0[t];
    f32x4 b = src0[t + 256];
    __syncthreads();

    #pragma unroll
    for (int it = 0; it < CITER; ++it) {
        const int cur = it & 1;
        const int nxt = cur ^ 1;
        const int ntok = tok + CGRID;
        f32x4 a1 = a, b1 = b;
        if (it < CITER - 1) {
            if (t < TOPK) {
                const int er = e_rank[(size_t)ntok * TOPK + t];
                s_pos[nxt][t] = blockoff[(size_t)(er & 0xff) * NB + (ntok >> 4)] + (er >> 8);
                s_w[nxt][t]   = flat_w[(size_t)ntok * TOPK + t];
            }
            const f32x4* __restrict__ src1 = (const f32x4*)(x + (size_t)ntok * HID);
            a1 = src1[t];
            b1 = src1[t + 256];
        }
        #pragma unroll
        for (int k = 0; k < TOPK; ++k) {
            const float w = s_w[cur][k];
            f32x4* dst = (f32x4*)(out + (size_t)s_pos[cur][k] * HID);
            __builtin_nontemporal_store(a * w, dst + t);
            __builtin_nontemporal_store(b * w, dst + t + 256);
        }
        __syncthreads();   // next-iter meta visible; s_pos[cur] safe to reuse
        a = a1; b = b1; tok = ntok;
    }
}

extern "C" void kernel_launch(void* const* d_in, const int* in_sizes, int n_in,
                              void* d_out, int out_size, void* d_ws, size_t ws_size,
                              hipStream_t stream) {
    const float* x      = (const float*)d_in[0];   // inputs_flat [8192,2048]
    const float* logits = (const float*)d_in[1];   // router_logits [8192,64]
    float* out = (float*)d_out;

    char* ws = (char*)d_ws;
    int*   e_rank   = (int*)  (ws + 0);            // 65536*4 = 262144
    float* flat_w   = (float*)(ws + 262144);       // 262144
    int*   counts   = (int*)  (ws + 524288);       // 64*512*4 = 131072
    int*   blockoff = (int*)  (ws + 655360);       // 131072
    float* probpart = (float*)(ws + 786432);       // 131072

    k_route<<<NB, 256, 0, stream>>>(logits, e_rank, flat_w, counts, probpart);
    k_scan <<<1, 256, 0, stream>>>(counts, probpart, blockoff,
                                   out + OUT_GS_OFF, out + OUT_LB_OFF);
    k_copy <<<CGRID, 256, 0, stream>>>(x, e_rank, flat_w, blockoff, out);
}